// Round 7
// baseline (311.518 us; speedup 1.0000x reference)
//
#include <hip/hip_runtime.h>
#include <hip/hip_fp16.h>

namespace {
constexpr int kB  = 2;
constexpr int kL  = 1024;
constexpr int kDM = 1024;
constexpr int kDI = 2048;
constexpr int kPROJW = 8192;   // proj16 row: [x 0..2048 | z ..4096 | B ..6144 | C ..8192]
constexpr int kBL = 2048;
constexpr int kQ  = 32;        // chunk length
constexpr int kQH = 16;        // rows staged per phase
constexpr int kNC = 32;        // chunks per (b,n)
constexpr int kCvtX = kBL * kDM / 4;      // 524288 vec4
constexpr int kCvtW = 8224 * kDM / 4;     // 2105344 (8192 cvt rows + 32 dt rows -> WdtT)
constexpr int kCvtO = kDM * kDI / 4;      // 524288
constexpr int kCvtBlocks  = (kCvtX + kCvtW + kCvtO) / 256;  // 12320
constexpr int kNegABlocks = 8;
}

typedef float f4 __attribute__((ext_vector_type(4)));
typedef float f2 __attribute__((ext_vector_type(2)));
typedef _Float16 f16x8 __attribute__((ext_vector_type(8)));
typedef _Float16 f16x4 __attribute__((ext_vector_type(4)));
typedef _Float16 f16x2 __attribute__((ext_vector_type(2)));

__device__ __forceinline__ void async_ld16(const void* g, void* l) {
  __builtin_amdgcn_global_load_lds(
      (const __attribute__((address_space(1))) void*)g,
      (__attribute__((address_space(3))) void*)l, 16, 0, 0);
}

// ---------------------------------------------------------------------------
// K1: f32->f16 cvt of x / W_in(row-permuted) / W_out + WdtT pack + negA.
// ---------------------------------------------------------------------------
__global__ __launch_bounds__(256) void prep_inputs(
    const float* __restrict__ x, const float* __restrict__ W_in,
    const float* __restrict__ W_out, const float* __restrict__ A_log,
    _Float16* __restrict__ x16, _Float16* __restrict__ Wi16,
    _Float16* __restrict__ Wo16, float* __restrict__ WdtT,
    float* __restrict__ negA) {
  const int bid = blockIdx.x;
  const int tid = threadIdx.x;
  if (bid < kCvtBlocks) {
    int i = bid * 256 + tid;
    if (i < kCvtX) {
      const f4 v = ((const f4*)x)[i];
      f16x4 o; o[0]=(_Float16)v[0]; o[1]=(_Float16)v[1]; o[2]=(_Float16)v[2]; o[3]=(_Float16)v[3];
      ((f16x4*)x16)[i] = o;
    } else if (i < kCvtX + kCvtW) {
      i -= kCvtX;
      const int row = i >> 8;        // [0, 8224)
      const int cv  = i & 255;
      if (row < 8192) {
        int srow;
        if (row < 4096)      srow = row;
        else if (row < 6144) { const int m = row - 4096; srow = 4096 + (m >> 6) * 129 + (m & 63); }
        else                 { const int m = row - 6144; srow = 4096 + (m >> 6) * 129 + 64 + (m & 63); }
        const f4 v = ((const f4*)(W_in + (size_t)srow * kDM))[cv];
        f16x4 o; o[0]=(_Float16)v[0]; o[1]=(_Float16)v[1]; o[2]=(_Float16)v[2]; o[3]=(_Float16)v[3];
        ((f16x4*)(Wi16 + (size_t)row * kDM))[cv] = o;
      } else {
        const int h = row - 8192;    // dt row -> transposed f32 pack
        const f4 v = ((const f4*)(W_in + (size_t)(4096 + h * 129 + 128) * kDM))[cv];
        const int k = cv * 4;
        WdtT[(k + 0) * 32 + h] = v[0];
        WdtT[(k + 1) * 32 + h] = v[1];
        WdtT[(k + 2) * 32 + h] = v[2];
        WdtT[(k + 3) * 32 + h] = v[3];
      }
    } else {
      i -= kCvtX + kCvtW;
      const f4 v = ((const f4*)W_out)[i];
      f16x4 o; o[0]=(_Float16)v[0]; o[1]=(_Float16)v[1]; o[2]=(_Float16)v[2]; o[3]=(_Float16)v[3];
      ((f16x4*)Wo16)[i] = o;
    }
  } else {
    const int i = (bid - kCvtBlocks) * 256 + tid;
    if (i < 2048) negA[i] = -__expf(A_log[i]);
  }
}

// ---------------------------------------------------------------------------
// K1b: dtb = softplus(x @ Wdt^T + bias), f32 exact.
// ---------------------------------------------------------------------------
__global__ __launch_bounds__(256) void dt_gemm(
    const float* __restrict__ x, const float* __restrict__ WdtT,
    const float* __restrict__ dt_bias, float* __restrict__ dtb) {
  __shared__ alignas(16) float Xs[4][1024];   // 16 KB
  __shared__ float Ps[4][8][32];              // 4 KB
  const int tid = threadIdx.x;
  const int gm0 = blockIdx.x * 4;
#pragma unroll
  for (int q = 0; q < 4; ++q)
    *(f4*)&Xs[q][tid * 4 - (tid >> 8)] = *(const f4*)(x + (size_t)(gm0 + q) * kDM + tid * 4);
  __syncthreads();

  const int h  = tid & 31;
  const int sl = tid >> 5;
  const int k0 = sl * 128;
  float p0 = 0.f, p1 = 0.f, p2 = 0.f, p3 = 0.f;
#pragma unroll 8
  for (int i = 0; i < 128; ++i) {
    const float w = WdtT[(k0 + i) * 32 + h];
    p0 = fmaf(Xs[0][k0 + i], w, p0);
    p1 = fmaf(Xs[1][k0 + i], w, p1);
    p2 = fmaf(Xs[2][k0 + i], w, p2);
    p3 = fmaf(Xs[3][k0 + i], w, p3);
  }
  Ps[0][sl][h] = p0; Ps[1][sl][h] = p1; Ps[2][sl][h] = p2; Ps[3][sl][h] = p3;
  __syncthreads();
  if (tid < 128) {
    const int r = tid >> 5, hh = tid & 31;
    float v = 0.f;
#pragma unroll
    for (int s2 = 0; s2 < 8; ++s2) v += Ps[r][s2][hh];
    const float dtp = v + dt_bias[hh];
    const float dt  = (dtp > 20.f) ? dtp : log1pf(__expf(dtp));
    const int gm = gm0 + r;
    dtb[(size_t)((gm >> 10) * 32 + hh) * kL + (gm & 1023)] = dt;
  }
}

// ---------------------------------------------------------------------------
// K2: f16 GEMM 128x128, BK=32, f16 out, double-buffered LDS prefetch,
// XCD swizzle (nwg=1024). Unchanged (measured improvement).
// ---------------------------------------------------------------------------
__global__ __launch_bounds__(256) void gemm1(
    const _Float16* __restrict__ A, const _Float16* __restrict__ Bm,
    _Float16* __restrict__ C, int M, int N, int K) {
  __shared__ alignas(16) _Float16 As[2][128][32];
  __shared__ alignas(16) _Float16 Bs[2][128][32];
  const int tid  = threadIdx.x;
  const int lane = tid & 63;
  const int w    = tid >> 6;
  const int id   = blockIdx.x;
  const int sw   = (id & 7) * 128 + (id >> 3);   // XCD swizzle (nwg=1024)
  const int m0   = (sw & 15) * 128;              // M/128 = 16 tiles
  const int n0   = (sw >> 4) * 128;
  const int ra   = lane >> 2;
  const int cc   = (lane & 3) * 8;
  const int wm   = (w & 1) * 64;
  const int wn   = (w >> 1) * 64;
  const int l16  = lane & 15;
  const int l4   = lane >> 4;

  f4 acc[4][4] = {};

  auto stage = [&](int buf, int k0) {
#pragma unroll
    for (int q = 0; q < 2; ++q) {
      const int row = (w * 2 + q) * 16 + ra;
      async_ld16(A + (size_t)(m0 + row) * K + (k0 + cc), &As[buf][row][cc]);
      async_ld16(Bm + (size_t)(n0 + row) * K + (k0 + cc), &Bs[buf][row][cc]);
    }
  };
  auto compute = [&](int buf) {
    f16x8 af[4], bf[4];
#pragma unroll
    for (int t = 0; t < 4; ++t) {
      af[t] = *reinterpret_cast<const f16x8*>(&As[buf][wm + t * 16 + l16][l4 * 8]);
      bf[t] = *reinterpret_cast<const f16x8*>(&Bs[buf][wn + t * 16 + l16][l4 * 8]);
    }
#pragma unroll
    for (int i = 0; i < 4; ++i)
#pragma unroll
      for (int j = 0; j < 4; ++j)
        acc[i][j] = __builtin_amdgcn_mfma_f32_16x16x32_f16(af[i], bf[j], acc[i][j], 0, 0, 0);
  };

  stage(0, 0);
  __syncthreads();
  int cur = 0;
  for (int k0 = 0; k0 < K - 32; k0 += 32) {
    stage(cur ^ 1, k0 + 32);   // next tile in flight during compute
    compute(cur);
    __syncthreads();           // drains vmcnt(0): next buffer ready
    cur ^= 1;
  }
  compute(cur);                // last tile, no prefetch

  const int col = l16;      // C/D: col = lane&15, row = (lane>>4)*4 + reg
  const int r0  = l4 * 4;
#pragma unroll
  for (int i = 0; i < 4; ++i)
#pragma unroll
    for (int j = 0; j < 4; ++j) {
      const int gn = n0 + wn + j * 16 + col;
#pragma unroll
      for (int r = 0; r < 4; ++r) {
        const int gm = m0 + wm + i * 16 + r0 + r;
        C[(size_t)gm * N + gn] = (_Float16)acc[i][j][r];
      }
    }
}

// ---------------------------------------------------------------------------
// K3: scan pass 1. kNC=32 chunks of kQ=32 -> 2048 blocks x 128 thr
// (restores 16 waves/CU). 2-d-per-lane inner loop (halved LDS issue).
// Two kQH=16 stage/compute phases; B f16 (async), A f32.
// ---------------------------------------------------------------------------
__global__ __launch_bounds__(128) void scan_pass1(
    const _Float16* __restrict__ proj16, const float* __restrict__ dtb,
    const float* __restrict__ negA, const float* __restrict__ conv_w,
    const float* __restrict__ conv_b, float* __restrict__ H,
    float* __restrict__ sdt) {
  __shared__ alignas(16) float Ad[kQH][64];      // 4 KB
  __shared__ alignas(16) _Float16 Bd[kQH][64];   // 2 KB
  __shared__ alignas(16) _Float16 Xd[kQH][64];   // 2 KB
  __shared__ float dts[kQ];
  const int tid  = threadIdx.x;     // 0..127
  const int bn   = blockIdx.x >> 5;
  const int c    = blockIdx.x & (kNC - 1);
  const int lane = tid & 63;
  const int w    = tid >> 6;        // 0..1
  const int sg   = lane >> 4;
  const int dd   = lane & 15;
  const int b    = bn >> 5, n = bn & 31;
  const int l0   = c * kQ;
  const int d0   = w * 32 + dd * 2;

  f4 hA[4] = {}, hB[4] = {};

  for (int p = 0; p < 2; ++p) {
    const int r0 = p * kQH;
    // stage B raw f16 via async copy: 16 rows x 128B = one ld16 per thread
    {
      const int row = tid >> 3;
      const int ch  = (tid & 7) * 8;
      async_ld16(proj16 + (size_t)(b * kL + l0 + r0 + row) * kPROJW + 4096 + n * 64 + ch,
                 &Bd[row][ch]);
    }
    // stage A (exp) + conv/silu -> Xd: thread = (row = tid>>3, 8-col slice)
    {
      const int l  = tid >> 3;          // 0..15 local row
      const int q8 = (tid & 7) * 8;
      const int gl = l0 + r0 + l;
      const float dtl = dtb[(size_t)bn * kL + gl];
      if ((tid & 7) == 0) dts[r0 + l] = dtl;
#pragma unroll
      for (int j = 0; j < 8; ++j)
        Ad[l][q8 + j] = __expf(negA[n * 64 + q8 + j] * dtl);
      float acc[8];
#pragma unroll
      for (int j = 0; j < 8; ++j) acc[j] = conv_b[n * 64 + q8 + j];
#pragma unroll
      for (int jj = 0; jj < 4; ++jj) {
        const int r = gl - 3 + jj;
        if (r < 0) continue;
        const f16x8 v0 = *(const f16x8*)(proj16 + (size_t)(b * kL + r) * kPROJW + n * 64 + q8);
#pragma unroll
        for (int j = 0; j < 8; ++j)
          acc[j] += conv_w[(n * 64 + q8 + j) * 4 + jj] * (float)v0[j];
      }
      f16x8 o;
#pragma unroll
      for (int j = 0; j < 8; ++j)
        o[j] = (_Float16)(dtl * acc[j] / (1.f + __expf(-acc[j])));
      *(f16x8*)&Xd[l][q8] = o;
    }
    __syncthreads();

#pragma unroll 2
    for (int tt = 0; tt < kQH; ++tt) {
      const f16x2 xv = *(const f16x2*)&Xd[tt][d0];
      const float x0 = (float)xv[0], x1 = (float)xv[1];
      const f16x8 bv0 = *(const f16x8*)&Bd[tt][sg * 16];
      const f16x8 bv1 = *(const f16x8*)&Bd[tt][sg * 16 + 8];
#pragma unroll
      for (int q = 0; q < 4; ++q) {
        const f4 a = ((const f4*)&Ad[tt][sg * 16])[q];
        f4 bb;
#pragma unroll
        for (int i = 0; i < 4; ++i) {
          const int sj = q * 4 + i;
          bb[i] = (float)(sj < 8 ? bv0[sj & 7] : bv1[sj & 7]);
        }
        hA[q] = a * hA[q] + bb * x0;
        hB[q] = a * hB[q] + bb * x1;
      }
    }
    __syncthreads();
  }

  if (tid == 0) {
    float s = 0.f;
    for (int t = 0; t < kQ; ++t) s += dts[t];
    sdt[bn * kNC + c] = s;
  }

  float* hp = H + (((size_t)bn * kNC + c) * 64 + sg * 16) * 64 + d0;
#pragma unroll
  for (int q = 0; q < 4; ++q)
#pragma unroll
    for (int i = 0; i < 4; ++i) {
      f2 hv; hv[0] = hA[q][i]; hv[1] = hB[q][i];
      *(f2*)&hp[(size_t)(q * 4 + i) * 64] = hv;
    }
}

// ---------------------------------------------------------------------------
// K4: chunk stitching IN-PLACE: H[c] holds local sums on entry, carry-in
// h_in[c] on exit. h_in[c+1] = exp(negA_s*sdt[c])*h_in[c] + hloc[c].
// ---------------------------------------------------------------------------
__global__ __launch_bounds__(256) void scan_pass2(
    float* __restrict__ H, const float* __restrict__ sdt,
    const float* __restrict__ negA) {
  const int bn = blockIdx.x >> 2;
  const int dq = blockIdx.x & 3;
  const int n  = bn & 31;
  const int s  = threadIdx.x >> 2;
  const int d0 = dq * 16 + (threadIdx.x & 3) * 4;
  const float Aa = negA[n * 64 + s];
  f4 h = {};
  for (int c = 0; c < kNC; ++c) {
    const size_t off = (((size_t)bn * kNC + c) * 64 + s) * 64 + d0;
    const float ap = __expf(Aa * sdt[bn * kNC + c]);
    const f4 hl = *(const f4*)(H + off);   // local sums
    *(f4*)(H + off) = h;                   // overwrite with carry-in
    h = ap * h + hl;
  }
}

// ---------------------------------------------------------------------------
// K5: scan pass 3. Same geometry as pass1; B/C/Z raw f16 via async copy;
// A f32. Per-wave-t LDS: 8 b128 + 2 small (was 13 b128-class in R5).
// ---------------------------------------------------------------------------
__global__ __launch_bounds__(128) void scan_pass3(
    const _Float16* __restrict__ proj16, const float* __restrict__ dtb,
    const float* __restrict__ negA, const float* __restrict__ conv_w,
    const float* __restrict__ conv_b, const float* __restrict__ H,
    const float* __restrict__ Dv, _Float16* __restrict__ yin) {
  __shared__ alignas(16) float Ad[kQH][64];      // 4 KB
  __shared__ alignas(16) _Float16 Bd[kQH][64];   // 2 KB
  __shared__ alignas(16) _Float16 Cd[kQH][64];   // 2 KB
  __shared__ alignas(16) _Float16 Xd[kQH][64];   // 2 KB
  __shared__ alignas(16) _Float16 Zd[kQH][64];   // 2 KB
  __shared__ float rdt[kQH];
  const int tid  = threadIdx.x;     // 0..127
  const int bn   = blockIdx.x >> 5;
  const int c    = blockIdx.x & (kNC - 1);
  const int lane = tid & 63;
  const int w    = tid >> 6;        // 0..1
  const int sg   = lane >> 4;
  const int dd   = lane & 15;
  const int b    = bn >> 5, n = bn & 31;
  const int l0   = c * kQ;
  const int d0   = w * 32 + dd * 2;

  // h init from carry-in (registers, carried across both phases)
  f4 hA[4], hB[4];
  {
    const float* hp = H + (((size_t)bn * kNC + c) * 64 + sg * 16) * 64 + d0;
#pragma unroll
    for (int q = 0; q < 4; ++q)
#pragma unroll
      for (int i = 0; i < 4; ++i) {
        const f2 hv = *(const f2*)&hp[(size_t)(q * 4 + i) * 64];
        hA[q][i] = hv[0]; hB[q][i] = hv[1];
      }
  }
  const float Dn = Dv[n];
  _Float16* Yb = yin + (size_t)(b * kL + l0) * kDI + n * 64 + d0;

  for (int p = 0; p < 2; ++p) {
    const int r0 = p * kQH;
    // stage B,C,Z raw f16 via async copy (one ld16 per thread per buffer)
    {
      const int row = tid >> 3;
      const int ch  = (tid & 7) * 8;
      const _Float16* base = proj16 +
          (size_t)(b * kL + l0 + r0 + row) * kPROJW + n * 64 + ch;
      async_ld16(base + 4096, &Bd[row][ch]);
      async_ld16(base + 6144, &Cd[row][ch]);
      async_ld16(base + 2048, &Zd[row][ch]);
    }
    // stage A (exp) + conv/silu -> Xd + rdt
    {
      const int l  = tid >> 3;
      const int q8 = (tid & 7) * 8;
      const int gl = l0 + r0 + l;
      const float dtl = dtb[(size_t)bn * kL + gl];
      if ((tid & 7) == 0) rdt[l] = 1.0f / dtl;
#pragma unroll
      for (int j = 0; j < 8; ++j)
        Ad[l][q8 + j] = __expf(negA[n * 64 + q8 + j] * dtl);
      float acc[8];
#pragma unroll
      for (int j = 0; j < 8; ++j) acc[j] = conv_b[n * 64 + q8 + j];
#pragma unroll
      for (int jj = 0; jj < 4; ++jj) {
        const int r = gl - 3 + jj;
        if (r < 0) continue;
        const f16x8 v0 = *(const f16x8*)(proj16 + (size_t)(b * kL + r) * kPROJW + n * 64 + q8);
#pragma unroll
        for (int j = 0; j < 8; ++j)
          acc[j] += conv_w[(n * 64 + q8 + j) * 4 + jj] * (float)v0[j];
      }
      f16x8 o;
#pragma unroll
      for (int j = 0; j < 8; ++j)
        o[j] = (_Float16)(dtl * acc[j] / (1.f + __expf(-acc[j])));
      *(f16x8*)&Xd[l][q8] = o;
    }
    __syncthreads();

#pragma unroll 2
    for (int tt = 0; tt < kQH; ++tt) {
      const f16x2 xv = *(const f16x2*)&Xd[tt][d0];
      const float x0 = (float)xv[0], x1 = (float)xv[1];
      const f16x8 bv0 = *(const f16x8*)&Bd[tt][sg * 16];
      const f16x8 bv1 = *(const f16x8*)&Bd[tt][sg * 16 + 8];
      const f16x8 cv0 = *(const f16x8*)&Cd[tt][sg * 16];
      const f16x8 cv1 = *(const f16x8*)&Cd[tt][sg * 16 + 8];
      f4 pvA = {}, pvB = {};
#pragma unroll
      for (int q = 0; q < 4; ++q) {
        const f4 a = ((const f4*)&Ad[tt][sg * 16])[q];
        f4 bb, cc;
#pragma unroll
        for (int i = 0; i < 4; ++i) {
          const int sj = q * 4 + i;
          bb[i] = (float)(sj < 8 ? bv0[sj & 7] : bv1[sj & 7]);
          cc[i] = (float)(sj < 8 ? cv0[sj & 7] : cv1[sj & 7]);
        }
        hA[q] = a * hA[q] + bb * x0;
        hB[q] = a * hB[q] + bb * x1;
        pvA = pvA + cc * hA[q];
        pvB = pvB + cc * hB[q];
      }
      float pA = (pvA[0] + pvA[1]) + (pvA[2] + pvA[3]);
      float pB = (pvB[0] + pvB[1]) + (pvB[2] + pvB[3]);
      pA += __shfl_xor(pA, 16);
      pA += __shfl_xor(pA, 32);
      pB += __shfl_xor(pB, 16);
      pB += __shfl_xor(pB, 32);
      if (sg == 0) {
        const float rd = rdt[tt];
        const f16x2 zv = *(const f16x2*)&Zd[tt][d0];
        const float z0 = (float)zv[0], z1 = (float)zv[1];
        const float zs0 = z0 / (1.f + __expf(-z0));
        const float zs1 = z1 / (1.f + __expf(-z1));
        f16x2 yv;
        yv[0] = (_Float16)((pA + Dn * (x0 * rd)) * zs0);
        yv[1] = (_Float16)((pB + Dn * (x1 * rd)) * zs1);
        *(f16x2*)&Yb[(size_t)(r0 + tt) * kDI] = yv;
      }
    }
    __syncthreads();
  }
}

// ---------------------------------------------------------------------------
// K6: out[2048,1024] f32 = yin @ Wo16^T. 64x64 tile, BK=32, dbuf prefetch,
// XCD swizzle (nwg=512). Unchanged.
// ---------------------------------------------------------------------------
__global__ __launch_bounds__(256) void gemm_out(
    const _Float16* __restrict__ A, const _Float16* __restrict__ Bm,
    float* __restrict__ C) {
  __shared__ alignas(16) _Float16 As[2][64][32];
  __shared__ alignas(16) _Float16 Bs[2][64][32];
  const int tid  = threadIdx.x;
  const int lane = tid & 63;
  const int w    = tid >> 6;
  const int id   = blockIdx.x;
  const int sw   = (id & 7) * 64 + (id >> 3);    // XCD swizzle (nwg=512)
  const int m0   = (sw >> 4) * 64;               // 32 M-tiles
  const int n0   = (sw & 15) * 64;               // 16 N-tiles
  const int row  = tid >> 2;
  const int cc   = (tid & 3) * 8;
  const int wm   = (w & 1) * 32;
  const int wn   = (w >> 1) * 32;
  const int l16  = lane & 15;
  const int l4   = lane >> 4;

  f4 acc[2][2] = {};

  auto stage = [&](int buf, int k0) {
    async_ld16(A + (size_t)(m0 + row) * kDI + (k0 + cc), &As[buf][row][cc]);
    async_ld16(Bm + (size_t)(n0 + row) * kDI + (k0 + cc), &Bs[buf][row][cc]);
  };
  auto compute = [&](int buf) {
    f16x8 af[2], bf[2];
#pragma unroll
    for (int t = 0; t < 2; ++t) {
      af[t] = *reinterpret_cast<const f16x8*>(&As[buf][wm + t * 16 + l16][l4 * 8]);
      bf[t] = *reinterpret_cast<const f16x8*>(&Bs[buf][wn + t * 16 + l16][l4 * 8]);
    }
#pragma unroll
    for (int i = 0; i < 2; ++i)
#pragma unroll
      for (int j = 0; j < 2; ++j)
        acc[i][j] = __builtin_amdgcn_mfma_f32_16x16x32_f16(af[i], bf[j], acc[i][j], 0, 0, 0);
  };

  stage(0, 0);
  __syncthreads();
  int cur = 0;
  for (int k0 = 0; k0 < kDI - 32; k0 += 32) {
    stage(cur ^ 1, k0 + 32);
    compute(cur);
    __syncthreads();
    cur ^= 1;
  }
  compute(cur);

  const int col = l16;
  const int r0  = l4 * 4;
#pragma unroll
  for (int i = 0; i < 2; ++i)
#pragma unroll
    for (int j = 0; j < 2; ++j) {
      const int gn = n0 + wn + j * 16 + col;
#pragma unroll
      for (int r = 0; r < 4; ++r) {
        const int gm = m0 + wm + i * 16 + r0 + r;
        C[(size_t)gm * kDM + gn] = acc[i][j][r];
      }
    }
}

// ---------------------------------------------------------------------------
extern "C" void kernel_launch(void* const* d_in, const int* in_sizes, int n_in,
                              void* d_out, int out_size, void* d_ws, size_t ws_size,
                              hipStream_t stream) {
  const float* x      = (const float*)d_in[0];
  const float* W_in   = (const float*)d_in[1];
  const float* conv_w = (const float*)d_in[2];
  const float* conv_b = (const float*)d_in[3];
  const float* A_log  = (const float*)d_in[4];
  const float* Dv     = (const float*)d_in[5];
  const float* dt_b   = (const float*)d_in[6];
  const float* W_out  = (const float*)d_in[7];
  float* out = (float*)d_out;

  char* p = (char*)d_ws;
  _Float16* proj16 = (_Float16*)p; p += (size_t)kBL * kPROJW * 2;   // 33.6 MB
  float* dtb   = (float*)p; p += (size_t)64 * kL * 4;
  float* negA  = (float*)p; p += 2048 * 4;
  float* WdtT  = (float*)p; p += (size_t)1024 * 32 * 4;             // 128 KB
  float* sdt   = (float*)p; p += (size_t)64 * kNC * 4 + 3968;       // 8 KB + pad
  float* H     = (float*)p; p += (size_t)64 * kNC * 64 * 64 * 4;    // 33.6 MB (local sums -> carry-ins, in place)
  _Float16* yin  = (_Float16*)p; p += (size_t)kBL * kDI * 2;        // 8.4 MB
  _Float16* Wo16 = (_Float16*)p; p += (size_t)kDM * kDI * 2;        // 4.2 MB
  _Float16* x16  = (_Float16*)H;                    // alias (pre-scan phase)
  _Float16* Wi16 = x16 + (size_t)kBL * kDM;         // 16.8 MB, fits in H (33.6)

  prep_inputs<<<kCvtBlocks + kNegABlocks, 256, 0, stream>>>(
      x, W_in, W_out, A_log, x16, Wi16, Wo16, WdtT, negA);

  dt_gemm<<<kBL / 4, 256, 0, stream>>>(x, WdtT, dt_b, dtb);

  gemm1<<<(kBL / 128) * (kPROJW / 128), 256, 0, stream>>>(
      x16, Wi16, proj16, kBL, kPROJW, kDM);

  scan_pass1<<<64 * kNC, 128, 0, stream>>>(proj16, dtb, negA, conv_w, conv_b, H, sdt);
  scan_pass2<<<256, 256, 0, stream>>>(H, sdt, negA);
  scan_pass3<<<64 * kNC, 128, 0, stream>>>(proj16, dtb, negA, conv_w, conv_b, H, Dv, yin);

  gemm_out<<<(kBL / 64) * (kDM / 64), 256, 0, stream>>>(yin, Wo16, out);
}

// Round 8
// 291.836 us; speedup vs baseline: 1.0674x; 1.0674x over previous
//
#include <hip/hip_runtime.h>
#include <hip/hip_fp16.h>

namespace {
constexpr int kB  = 2;
constexpr int kL  = 1024;
constexpr int kDM = 1024;
constexpr int kDI = 2048;
constexpr int kPROJW = 8192;   // proj16 row: [x 0..2048 | z ..4096 | B ..6144 | C ..8192]
constexpr int kBL = 2048;
constexpr int kQ  = 32;        // chunk length
constexpr int kQH = 16;        // rows staged per phase
constexpr int kNC = 32;        // chunks per (b,n)
constexpr int kCvtX = kBL * kDM / 4;      // 524288 vec4
constexpr int kCvtW = 8224 * kDM / 4;     // 2105344 (8192 cvt rows + 32 dt rows -> WdtT)
constexpr int kCvtO = kDM * kDI / 4;      // 524288
constexpr int kCvtBlocks  = (kCvtX + kCvtW + kCvtO) / 256;  // 12320
constexpr int kNegABlocks = 8;
}

typedef float f4 __attribute__((ext_vector_type(4)));
typedef float f2 __attribute__((ext_vector_type(2)));
typedef _Float16 f16x8 __attribute__((ext_vector_type(8)));
typedef _Float16 f16x4 __attribute__((ext_vector_type(4)));
typedef _Float16 f16x2 __attribute__((ext_vector_type(2)));

__device__ __forceinline__ void async_ld16(const void* g, void* l) {
  __builtin_amdgcn_global_load_lds(
      (const __attribute__((address_space(1))) void*)g,
      (__attribute__((address_space(3))) void*)l, 16, 0, 0);
}

__device__ __forceinline__ float sigm(float v) {
  return __builtin_amdgcn_rcpf(1.f + __expf(-v));   // 1-instr rcp vs IEEE div
}

// ---------------------------------------------------------------------------
// K1: f32->f16 cvt of x / W_in(row-permuted) / W_out + WdtT pack + negA.
// ---------------------------------------------------------------------------
__global__ __launch_bounds__(256) void prep_inputs(
    const float* __restrict__ x, const float* __restrict__ W_in,
    const float* __restrict__ W_out, const float* __restrict__ A_log,
    _Float16* __restrict__ x16, _Float16* __restrict__ Wi16,
    _Float16* __restrict__ Wo16, float* __restrict__ WdtT,
    float* __restrict__ negA) {
  const int bid = blockIdx.x;
  const int tid = threadIdx.x;
  if (bid < kCvtBlocks) {
    int i = bid * 256 + tid;
    if (i < kCvtX) {
      const f4 v = ((const f4*)x)[i];
      f16x4 o; o[0]=(_Float16)v[0]; o[1]=(_Float16)v[1]; o[2]=(_Float16)v[2]; o[3]=(_Float16)v[3];
      ((f16x4*)x16)[i] = o;
    } else if (i < kCvtX + kCvtW) {
      i -= kCvtX;
      const int row = i >> 8;        // [0, 8224)
      const int cv  = i & 255;
      if (row < 8192) {
        int srow;
        if (row < 4096)      srow = row;
        else if (row < 6144) { const int m = row - 4096; srow = 4096 + (m >> 6) * 129 + (m & 63); }
        else                 { const int m = row - 6144; srow = 4096 + (m >> 6) * 129 + 64 + (m & 63); }
        const f4 v = ((const f4*)(W_in + (size_t)srow * kDM))[cv];
        f16x4 o; o[0]=(_Float16)v[0]; o[1]=(_Float16)v[1]; o[2]=(_Float16)v[2]; o[3]=(_Float16)v[3];
        ((f16x4*)(Wi16 + (size_t)row * kDM))[cv] = o;
      } else {
        const int h = row - 8192;    // dt row -> transposed f32 pack
        const f4 v = ((const f4*)(W_in + (size_t)(4096 + h * 129 + 128) * kDM))[cv];
        const int k = cv * 4;
        WdtT[(k + 0) * 32 + h] = v[0];
        WdtT[(k + 1) * 32 + h] = v[1];
        WdtT[(k + 2) * 32 + h] = v[2];
        WdtT[(k + 3) * 32 + h] = v[3];
      }
    } else {
      i -= kCvtX + kCvtW;
      const f4 v = ((const f4*)W_out)[i];
      f16x4 o; o[0]=(_Float16)v[0]; o[1]=(_Float16)v[1]; o[2]=(_Float16)v[2]; o[3]=(_Float16)v[3];
      ((f16x4*)Wo16)[i] = o;
    }
  } else {
    const int i = (bid - kCvtBlocks) * 256 + tid;
    if (i < 2048) negA[i] = -__expf(A_log[i]);
  }
}

// ---------------------------------------------------------------------------
// K1b: dtb = softplus(x @ Wdt^T + bias), f32 exact.
// ---------------------------------------------------------------------------
__global__ __launch_bounds__(256) void dt_gemm(
    const float* __restrict__ x, const float* __restrict__ WdtT,
    const float* __restrict__ dt_bias, float* __restrict__ dtb) {
  __shared__ alignas(16) float Xs[4][1024];   // 16 KB
  __shared__ float Ps[4][8][32];              // 4 KB
  const int tid = threadIdx.x;
  const int gm0 = blockIdx.x * 4;
#pragma unroll
  for (int q = 0; q < 4; ++q)
    *(f4*)&Xs[q][tid * 4 - (tid >> 8)] = *(const f4*)(x + (size_t)(gm0 + q) * kDM + tid * 4);
  __syncthreads();

  const int h  = tid & 31;
  const int sl = tid >> 5;
  const int k0 = sl * 128;
  float p0 = 0.f, p1 = 0.f, p2 = 0.f, p3 = 0.f;
#pragma unroll 8
  for (int i = 0; i < 128; ++i) {
    const float w = WdtT[(k0 + i) * 32 + h];
    p0 = fmaf(Xs[0][k0 + i], w, p0);
    p1 = fmaf(Xs[1][k0 + i], w, p1);
    p2 = fmaf(Xs[2][k0 + i], w, p2);
    p3 = fmaf(Xs[3][k0 + i], w, p3);
  }
  Ps[0][sl][h] = p0; Ps[1][sl][h] = p1; Ps[2][sl][h] = p2; Ps[3][sl][h] = p3;
  __syncthreads();
  if (tid < 128) {
    const int r = tid >> 5, hh = tid & 31;
    float v = 0.f;
#pragma unroll
    for (int s2 = 0; s2 < 8; ++s2) v += Ps[r][s2][hh];
    const float dtp = v + dt_bias[hh];
    const float dt  = (dtp > 20.f) ? dtp : log1pf(__expf(dtp));
    const int gm = gm0 + r;
    dtb[(size_t)((gm >> 10) * 32 + hh) * kL + (gm & 1023)] = dt;
  }
}

// ---------------------------------------------------------------------------
// K2: f16 GEMM 128x128, BK=32, f16 out, double-buffered LDS prefetch,
// XCD swizzle (nwg=1024). Unchanged (measured improvement).
// ---------------------------------------------------------------------------
__global__ __launch_bounds__(256) void gemm1(
    const _Float16* __restrict__ A, const _Float16* __restrict__ Bm,
    _Float16* __restrict__ C, int M, int N, int K) {
  __shared__ alignas(16) _Float16 As[2][128][32];
  __shared__ alignas(16) _Float16 Bs[2][128][32];
  const int tid  = threadIdx.x;
  const int lane = tid & 63;
  const int w    = tid >> 6;
  const int id   = blockIdx.x;
  const int sw   = (id & 7) * 128 + (id >> 3);   // XCD swizzle (nwg=1024)
  const int m0   = (sw & 15) * 128;              // M/128 = 16 tiles
  const int n0   = (sw >> 4) * 128;
  const int ra   = lane >> 2;
  const int cc   = (lane & 3) * 8;
  const int wm   = (w & 1) * 64;
  const int wn   = (w >> 1) * 64;
  const int l16  = lane & 15;
  const int l4   = lane >> 4;

  f4 acc[4][4] = {};

  auto stage = [&](int buf, int k0) {
#pragma unroll
    for (int q = 0; q < 2; ++q) {
      const int row = (w * 2 + q) * 16 + ra;
      async_ld16(A + (size_t)(m0 + row) * K + (k0 + cc), &As[buf][row][cc]);
      async_ld16(Bm + (size_t)(n0 + row) * K + (k0 + cc), &Bs[buf][row][cc]);
    }
  };
  auto compute = [&](int buf) {
    f16x8 af[4], bf[4];
#pragma unroll
    for (int t = 0; t < 4; ++t) {
      af[t] = *reinterpret_cast<const f16x8*>(&As[buf][wm + t * 16 + l16][l4 * 8]);
      bf[t] = *reinterpret_cast<const f16x8*>(&Bs[buf][wn + t * 16 + l16][l4 * 8]);
    }
#pragma unroll
    for (int i = 0; i < 4; ++i)
#pragma unroll
      for (int j = 0; j < 4; ++j)
        acc[i][j] = __builtin_amdgcn_mfma_f32_16x16x32_f16(af[i], bf[j], acc[i][j], 0, 0, 0);
  };

  stage(0, 0);
  __syncthreads();
  int cur = 0;
  for (int k0 = 0; k0 < K - 32; k0 += 32) {
    stage(cur ^ 1, k0 + 32);   // next tile in flight during compute
    compute(cur);
    __syncthreads();           // drains vmcnt(0): next buffer ready
    cur ^= 1;
  }
  compute(cur);                // last tile, no prefetch

  const int col = l16;      // C/D: col = lane&15, row = (lane>>4)*4 + reg
  const int r0  = l4 * 4;
#pragma unroll
  for (int i = 0; i < 4; ++i)
#pragma unroll
    for (int j = 0; j < 4; ++j) {
      const int gn = n0 + wn + j * 16 + col;
#pragma unroll
      for (int r = 0; r < 4; ++r) {
        const int gm = m0 + wm + i * 16 + r0 + r;
        C[(size_t)gm * N + gn] = (_Float16)acc[i][j][r];
      }
    }
}

// ---------------------------------------------------------------------------
// K3: scan pass 1. 2 heads (bn) per 256-thr block: wave w -> (hb=w>>1 head,
// wd=w&1 d-half). Lane (sg,dd): s in [16sg,+16), d = {d0,d0+1}. ALL-f32 LDS
// (A exp'd, B cvt'd, X=xdt f32) -> zero inner-loop cvts, 12 b128/wave-t per
// 32 d. LDS 24 KB -> 4+ blocks/CU, grid 1024 -> 16 waves/CU.
// ---------------------------------------------------------------------------
__global__ __launch_bounds__(256) void scan_pass1(
    const _Float16* __restrict__ proj16, const float* __restrict__ dtb,
    const float* __restrict__ negA, const float* __restrict__ conv_w,
    const float* __restrict__ conv_b, float* __restrict__ H,
    float* __restrict__ sdt) {
  __shared__ alignas(16) float Ad[2][kQH][64];   // 8 KB
  __shared__ alignas(16) float Bd[2][kQH][64];   // 8 KB
  __shared__ alignas(16) float Xd[2][kQH][64];   // 8 KB (xdt f32)
  __shared__ float dts[2][kQ];
  const int tid  = threadIdx.x;
  const int g    = blockIdx.x;
  const int c    = g & (kNC - 1);
  const int bnp  = g >> 5;
  const int lane = tid & 63;
  const int w    = tid >> 6;
  const int hb   = w >> 1;
  const int wd   = w & 1;
  const int sg   = lane >> 4;
  const int dd   = lane & 15;
  const int bn   = bnp * 2 + hb;
  const int b    = bn >> 5, n = bn & 31;
  const int l0   = c * kQ;
  const int d0   = wd * 32 + dd * 2;
  const int t128 = tid & 127;
  const int shb  = tid >> 7;   // staging: which head this thread serves

  f4 hA[4] = {}, hB[4] = {};

  for (int p = 0; p < 2; ++p) {
    const int r0 = p * kQH;
    // ---- stage (128 thr per head): row = t128>>3, 8-ch slice ----
    {
      const int sn  = (bnp * 2 + shb) & 31;
      const int sb  = (bnp * 2 + shb) >> 5;
      const int row = t128 >> 3;
      const int ch  = (t128 & 7) * 8;
      const int gl  = l0 + r0 + row;
      const float dtl = dtb[(size_t)(bnp * 2 + shb) * kL + gl];
      if ((t128 & 7) == 0) dts[shb][r0 + row] = dtl;
      // B: f16 -> f32
      const f16x8 vb = *(const f16x8*)(proj16 +
          (size_t)(sb * kL + gl) * kPROJW + 4096 + sn * 64 + ch);
      f4 blo, bhi;
      blo[0]=(float)vb[0]; blo[1]=(float)vb[1]; blo[2]=(float)vb[2]; blo[3]=(float)vb[3];
      bhi[0]=(float)vb[4]; bhi[1]=(float)vb[5]; bhi[2]=(float)vb[6]; bhi[3]=(float)vb[7];
      *(f4*)&Bd[shb][row][ch]     = blo;
      *(f4*)&Bd[shb][row][ch + 4] = bhi;
      // A: exp
#pragma unroll
      for (int j = 0; j < 8; ++j)
        Ad[shb][row][ch + j] = __expf(negA[sn * 64 + ch + j] * dtl);
      // conv + silu -> xdt (f32)
      float acc[8];
#pragma unroll
      for (int j = 0; j < 8; ++j) acc[j] = conv_b[sn * 64 + ch + j];
#pragma unroll
      for (int jj = 0; jj < 4; ++jj) {
        const int r = gl - 3 + jj;
        if (r < 0) continue;
        const f16x8 v0 = *(const f16x8*)(proj16 + (size_t)(sb * kL + r) * kPROJW + sn * 64 + ch);
#pragma unroll
        for (int j = 0; j < 8; ++j)
          acc[j] += conv_w[(sn * 64 + ch + j) * 4 + jj] * (float)v0[j];
      }
#pragma unroll
      for (int j = 0; j < 8; ++j)
        Xd[shb][row][ch + j] = dtl * (acc[j] * sigm(acc[j]));
    }
    __syncthreads();

    // ---- compute ----
#pragma unroll 2
    for (int tt = 0; tt < kQH; ++tt) {
      const f2 xv = *(const f2*)&Xd[hb][tt][d0];
      const float x0 = xv[0], x1 = xv[1];
#pragma unroll
      for (int q = 0; q < 4; ++q) {
        const f4 a  = ((const f4*)&Ad[hb][tt][sg * 16])[q];
        const f4 bb = ((const f4*)&Bd[hb][tt][sg * 16])[q];
        hA[q] = a * hA[q] + bb * x0;
        hB[q] = a * hB[q] + bb * x1;
      }
    }
    __syncthreads();
  }

  if (t128 == 0) {     // tid 0 -> head 0, tid 128 -> head 1
    float s = 0.f;
    for (int t = 0; t < kQ; ++t) s += dts[shb][t];
    sdt[(bnp * 2 + shb) * kNC + c] = s;
  }

  float* hp = H + (((size_t)bn * kNC + c) * 64 + sg * 16) * 64 + d0;
#pragma unroll
  for (int q = 0; q < 4; ++q)
#pragma unroll
    for (int i = 0; i < 4; ++i) {
      f2 hv; hv[0] = hA[q][i]; hv[1] = hB[q][i];
      *(f2*)&hp[(size_t)(q * 4 + i) * 64] = hv;
    }
}

// ---------------------------------------------------------------------------
// K4: chunk stitching IN-PLACE: H[c] holds local sums on entry, carry-in
// h_in[c] on exit. h_in[c+1] = exp(negA_s*sdt[c])*h_in[c] + hloc[c].
// ---------------------------------------------------------------------------
__global__ __launch_bounds__(256) void scan_pass2(
    float* __restrict__ H, const float* __restrict__ sdt,
    const float* __restrict__ negA) {
  const int bn = blockIdx.x >> 2;
  const int dq = blockIdx.x & 3;
  const int n  = bn & 31;
  const int s  = threadIdx.x >> 2;
  const int d0 = dq * 16 + (threadIdx.x & 3) * 4;
  const float Aa = negA[n * 64 + s];
  f4 h = {};
  for (int c = 0; c < kNC; ++c) {
    const size_t off = (((size_t)bn * kNC + c) * 64 + s) * 64 + d0;
    const float ap = __expf(Aa * sdt[bn * kNC + c]);
    const f4 hl = *(const f4*)(H + off);   // local sums
    *(f4*)(H + off) = h;                   // overwrite with carry-in
    h = ap * h + hl;
  }
}

// ---------------------------------------------------------------------------
// K5: scan pass 3. Same 2-head packing as pass1; A/B/C/X f32 (no inner cvt),
// Xs = f16 silu (D-term), Zd raw f16 (async). LDS 36 KB -> 4 blocks/CU.
// Per wave-t: 12 b128 + 1 b64 for 32 d of coverage (half of R5 per d).
// ---------------------------------------------------------------------------
__global__ __launch_bounds__(256) void scan_pass3(
    const _Float16* __restrict__ proj16, const float* __restrict__ dtb,
    const float* __restrict__ negA, const float* __restrict__ conv_w,
    const float* __restrict__ conv_b, const float* __restrict__ H,
    const float* __restrict__ Dv, _Float16* __restrict__ yin) {
  __shared__ alignas(16) float Ad[2][kQH][64];     // 8 KB
  __shared__ alignas(16) float Bd[2][kQH][64];     // 8 KB
  __shared__ alignas(16) float Cd[2][kQH][64];     // 8 KB
  __shared__ alignas(16) float Xd[2][kQH][64];     // 8 KB (xdt f32)
  __shared__ alignas(16) _Float16 Xs[2][kQH][64];  // 2 KB (xsilu f16)
  __shared__ alignas(16) _Float16 Zd[2][kQH][64];  // 2 KB (raw z)
  const int tid  = threadIdx.x;
  const int g    = blockIdx.x;
  const int c    = g & (kNC - 1);
  const int bnp  = g >> 5;
  const int lane = tid & 63;
  const int w    = tid >> 6;
  const int hb   = w >> 1;
  const int wd   = w & 1;
  const int sg   = lane >> 4;
  const int dd   = lane & 15;
  const int bn   = bnp * 2 + hb;
  const int b    = bn >> 5, n = bn & 31;
  const int l0   = c * kQ;
  const int d0   = wd * 32 + dd * 2;
  const int t128 = tid & 127;
  const int shb  = tid >> 7;

  // h init from carry-in (registers, carried across both phases)
  f4 hA[4], hB[4];
  {
    const float* hp = H + (((size_t)bn * kNC + c) * 64 + sg * 16) * 64 + d0;
#pragma unroll
    for (int q = 0; q < 4; ++q)
#pragma unroll
      for (int i = 0; i < 4; ++i) {
        const f2 hv = *(const f2*)&hp[(size_t)(q * 4 + i) * 64];
        hA[q][i] = hv[0]; hB[q][i] = hv[1];
      }
  }
  const float Dn = Dv[n];
  _Float16* Yb = yin + (size_t)(b * kL + l0) * kDI + n * 64 + d0;

  for (int p = 0; p < 2; ++p) {
    const int r0 = p * kQH;
    // ---- stage (128 thr per head) ----
    {
      const int sn  = (bnp * 2 + shb) & 31;
      const int sb  = (bnp * 2 + shb) >> 5;
      const int row = t128 >> 3;
      const int ch  = (t128 & 7) * 8;
      const int gl  = l0 + r0 + row;
      const _Float16* base = proj16 + (size_t)(sb * kL + gl) * kPROJW + sn * 64 + ch;
      async_ld16(base + 2048, &Zd[shb][row][ch]);
      const float dtl = dtb[(size_t)(bnp * 2 + shb) * kL + gl];
      // B, C: f16 -> f32
      const f16x8 vb = *(const f16x8*)(base + 4096);
      const f16x8 vc = *(const f16x8*)(base + 6144);
      f4 blo, bhi, clo, chi;
      blo[0]=(float)vb[0]; blo[1]=(float)vb[1]; blo[2]=(float)vb[2]; blo[3]=(float)vb[3];
      bhi[0]=(float)vb[4]; bhi[1]=(float)vb[5]; bhi[2]=(float)vb[6]; bhi[3]=(float)vb[7];
      clo[0]=(float)vc[0]; clo[1]=(float)vc[1]; clo[2]=(float)vc[2]; clo[3]=(float)vc[3];
      chi[0]=(float)vc[4]; chi[1]=(float)vc[5]; chi[2]=(float)vc[6]; chi[3]=(float)vc[7];
      *(f4*)&Bd[shb][row][ch]     = blo;
      *(f4*)&Bd[shb][row][ch + 4] = bhi;
      *(f4*)&Cd[shb][row][ch]     = clo;
      *(f4*)&Cd[shb][row][ch + 4] = chi;
      // A: exp
#pragma unroll
      for (int j = 0; j < 8; ++j)
        Ad[shb][row][ch + j] = __expf(negA[sn * 64 + ch + j] * dtl);
      // conv + silu -> xsilu (f16) and xdt (f32)
      float acc[8];
#pragma unroll
      for (int j = 0; j < 8; ++j) acc[j] = conv_b[sn * 64 + ch + j];
#pragma unroll
      for (int jj = 0; jj < 4; ++jj) {
        const int r = gl - 3 + jj;
        if (r < 0) continue;
        const f16x8 v0 = *(const f16x8*)(proj16 + (size_t)(sb * kL + r) * kPROJW + sn * 64 + ch);
#pragma unroll
        for (int j = 0; j < 8; ++j)
          acc[j] += conv_w[(sn * 64 + ch + j) * 4 + jj] * (float)v0[j];
      }
      f16x8 xo;
#pragma unroll
      for (int j = 0; j < 8; ++j) {
        const float xs = acc[j] * sigm(acc[j]);
        xo[j] = (_Float16)xs;
        Xd[shb][row][ch + j] = dtl * xs;
      }
      *(f16x8*)&Xs[shb][row][ch] = xo;
    }
    __syncthreads();

    // ---- compute ----
#pragma unroll 2
    for (int tt = 0; tt < kQH; ++tt) {
      const f2 xv = *(const f2*)&Xd[hb][tt][d0];
      const float x0 = xv[0], x1 = xv[1];
      f4 pvA = {}, pvB = {};
#pragma unroll
      for (int q = 0; q < 4; ++q) {
        const f4 a  = ((const f4*)&Ad[hb][tt][sg * 16])[q];
        const f4 bb = ((const f4*)&Bd[hb][tt][sg * 16])[q];
        const f4 cc = ((const f4*)&Cd[hb][tt][sg * 16])[q];
        hA[q] = a * hA[q] + bb * x0;
        hB[q] = a * hB[q] + bb * x1;
        pvA = pvA + cc * hA[q];
        pvB = pvB + cc * hB[q];
      }
      float pA = (pvA[0] + pvA[1]) + (pvA[2] + pvA[3]);
      float pB = (pvB[0] + pvB[1]) + (pvB[2] + pvB[3]);
      pA += __shfl_xor(pA, 16);
      pA += __shfl_xor(pA, 32);
      pB += __shfl_xor(pB, 16);
      pB += __shfl_xor(pB, 32);
      if (sg == 0) {
        const f16x2 zv = *(const f16x2*)&Zd[hb][tt][d0];
        const f16x2 xs = *(const f16x2*)&Xs[hb][tt][d0];
        const float z0 = (float)zv[0], z1 = (float)zv[1];
        const float y0 = (pA + Dn * (float)xs[0]) * (z0 * sigm(z0));
        const float y1 = (pB + Dn * (float)xs[1]) * (z1 * sigm(z1));
        f16x2 yv; yv[0] = (_Float16)y0; yv[1] = (_Float16)y1;
        *(f16x2*)&Yb[(size_t)(r0 + tt) * kDI] = yv;
      }
    }
    __syncthreads();
  }
}

// ---------------------------------------------------------------------------
// K6: out[2048,1024] f32 = yin @ Wo16^T. 64x64 tile, BK=32, dbuf prefetch,
// XCD swizzle (nwg=512). Unchanged.
// ---------------------------------------------------------------------------
__global__ __launch_bounds__(256) void gemm_out(
    const _Float16* __restrict__ A, const _Float16* __restrict__ Bm,
    float* __restrict__ C) {
  __shared__ alignas(16) _Float16 As[2][64][32];
  __shared__ alignas(16) _Float16 Bs[2][64][32];
  const int tid  = threadIdx.x;
  const int lane = tid & 63;
  const int w    = tid >> 6;
  const int id   = blockIdx.x;
  const int sw   = (id & 7) * 64 + (id >> 3);    // XCD swizzle (nwg=512)
  const int m0   = (sw >> 4) * 64;               // 32 M-tiles
  const int n0   = (sw & 15) * 64;               // 16 N-tiles
  const int row  = tid >> 2;
  const int cc   = (tid & 3) * 8;
  const int wm   = (w & 1) * 32;
  const int wn   = (w >> 1) * 32;
  const int l16  = lane & 15;
  const int l4   = lane >> 4;

  f4 acc[2][2] = {};

  auto stage = [&](int buf, int k0) {
    async_ld16(A + (size_t)(m0 + row) * kDI + (k0 + cc), &As[buf][row][cc]);
    async_ld16(Bm + (size_t)(n0 + row) * kDI + (k0 + cc), &Bs[buf][row][cc]);
  };
  auto compute = [&](int buf) {
    f16x8 af[2], bf[2];
#pragma unroll
    for (int t = 0; t < 2; ++t) {
      af[t] = *reinterpret_cast<const f16x8*>(&As[buf][wm + t * 16 + l16][l4 * 8]);
      bf[t] = *reinterpret_cast<const f16x8*>(&Bs[buf][wn + t * 16 + l16][l4 * 8]);
    }
#pragma unroll
    for (int i = 0; i < 2; ++i)
#pragma unroll
      for (int j = 0; j < 2; ++j)
        acc[i][j] = __builtin_amdgcn_mfma_f32_16x16x32_f16(af[i], bf[j], acc[i][j], 0, 0, 0);
  };

  stage(0, 0);
  __syncthreads();
  int cur = 0;
  for (int k0 = 0; k0 < kDI - 32; k0 += 32) {
    stage(cur ^ 1, k0 + 32);
    compute(cur);
    __syncthreads();
    cur ^= 1;
  }
  compute(cur);

  const int col = l16;
  const int r0  = l4 * 4;
#pragma unroll
  for (int i = 0; i < 2; ++i)
#pragma unroll
    for (int j = 0; j < 2; ++j) {
      const int gn = n0 + wn + j * 16 + col;
#pragma unroll
      for (int r = 0; r < 4; ++r) {
        const int gm = m0 + wm + i * 16 + r0 + r;
        C[(size_t)gm * kDM + gn] = acc[i][j][r];
      }
    }
}

// ---------------------------------------------------------------------------
extern "C" void kernel_launch(void* const* d_in, const int* in_sizes, int n_in,
                              void* d_out, int out_size, void* d_ws, size_t ws_size,
                              hipStream_t stream) {
  const float* x      = (const float*)d_in[0];
  const float* W_in   = (const float*)d_in[1];
  const float* conv_w = (const float*)d_in[2];
  const float* conv_b = (const float*)d_in[3];
  const float* A_log  = (const float*)d_in[4];
  const float* Dv     = (const float*)d_in[5];
  const float* dt_b   = (const float*)d_in[6];
  const float* W_out  = (const float*)d_in[7];
  float* out = (float*)d_out;

  char* p = (char*)d_ws;
  _Float16* proj16 = (_Float16*)p; p += (size_t)kBL * kPROJW * 2;   // 33.6 MB
  float* dtb   = (float*)p; p += (size_t)64 * kL * 4;
  float* negA  = (float*)p; p += 2048 * 4;
  float* WdtT  = (float*)p; p += (size_t)1024 * 32 * 4;             // 128 KB
  float* sdt   = (float*)p; p += (size_t)64 * kNC * 4 + 3968;       // 8 KB + pad
  float* H     = (float*)p; p += (size_t)64 * kNC * 64 * 64 * 4;    // 33.6 MB (local sums -> carry-ins, in place)
  _Float16* yin  = (_Float16*)p; p += (size_t)kBL * kDI * 2;        // 8.4 MB
  _Float16* Wo16 = (_Float16*)p; p += (size_t)kDM * kDI * 2;        // 4.2 MB
  _Float16* x16  = (_Float16*)H;                    // alias (pre-scan phase)
  _Float16* Wi16 = x16 + (size_t)kBL * kDM;         // 16.8 MB, fits in H (33.6)

  prep_inputs<<<kCvtBlocks + kNegABlocks, 256, 0, stream>>>(
      x, W_in, W_out, A_log, x16, Wi16, Wo16, WdtT, negA);

  dt_gemm<<<kBL / 4, 256, 0, stream>>>(x, WdtT, dt_b, dtb);

  gemm1<<<(kBL / 128) * (kPROJW / 128), 256, 0, stream>>>(
      x16, Wi16, proj16, kBL, kPROJW, kDM);

  scan_pass1<<<(64 / 2) * kNC, 256, 0, stream>>>(proj16, dtb, negA, conv_w, conv_b, H, sdt);
  scan_pass2<<<256, 256, 0, stream>>>(H, sdt, negA);
  scan_pass3<<<(64 / 2) * kNC, 256, 0, stream>>>(proj16, dtb, negA, conv_w, conv_b, H, Dv, yin);

  gemm_out<<<(kBL / 64) * (kDM / 64), 256, 0, stream>>>(yin, Wo16, out);
}